// Round 4
// baseline (2002.374 us; speedup 1.0000x reference)
//
#include <hip/hip_runtime.h>

#define B_ 64
#define T_ 256
#define E_ 256
#define H_ 256
#define G4 1024   // 4*H
#define L_ 9
#define SENT 0xFFFFFFFFu

typedef __attribute__((ext_vector_type(8))) short bf16x8;
typedef __attribute__((ext_vector_type(4))) float f32x4;
typedef __attribute__((ext_vector_type(4))) unsigned uint4v;
typedef _Float16 half2v __attribute__((ext_vector_type(2)));

__device__ __forceinline__ ushort f2bf(float x){
  unsigned u = __float_as_uint(x);
  unsigned r = (u + 0x7FFFu + ((u >> 16) & 1u)) >> 16;
  return (ushort)r;
}
__device__ __forceinline__ float bf2f(unsigned u16v){
  return __uint_as_float(u16v << 16);
}
__device__ __forceinline__ float fsig(float x){
  return __builtin_amdgcn_rcpf(1.f + __expf(-x));
}
__device__ __forceinline__ float ftanh(float x){
  return 1.f - 2.f * __builtin_amdgcn_rcpf(__expf(2.f * x) + 1.f);
}

// ===== fused prep: WT | UT | gather | hbuf-init | seqlen =====
__global__ void k_prep(const int* __restrict__ inp, const float* __restrict__ emb,
                       const float* __restrict__ Wf, const float* __restrict__ Wb,
                       const float* __restrict__ Uf, const float* __restrict__ Ub,
                       ushort* __restrict__ WT, ushort* __restrict__ UT,
                       ushort* __restrict__ X, int* __restrict__ lens,
                       float* __restrict__ out_len, uint4* __restrict__ hbuf4){
  int bid = blockIdx.x, tid = threadIdx.x;
  if (bid < 2048){                                   // W -> bf16 transposed [dir][n][k]
    int idx = bid * 256 + tid;
    int dir = idx >> 18; int rem = idx & 262143;
    int n = rem >> 8, k = rem & 255;
    const float* W = dir ? Wb : Wf;
    WT[idx] = f2bf(W[k * G4 + n]);
  } else if (bid < 4096){                            // U -> bf16 transposed [dir][C][k]
    int idx = (bid - 2048) * 256 + tid;
    int dir = idx >> 18; int rem = idx & 262143;
    int C = rem >> 8, k = rem & 255;
    const float* U = dir ? Ub : Uf;
    UT[idx] = f2bf(U[k * G4 + C]);
  } else if (bid < 6144){                            // X = bf16(emb[inp])
    int idx = (bid - 4096) * 256 + tid;
    int m = idx >> 5, koff = (idx & 31) * 8;
    int tok = inp[m];
    const float* src = emb + (size_t)tok * E_ + koff;
    float4 a = *(const float4*)src;
    float4 b = *(const float4*)(src + 4);
    uint4 o;
    o.x = (unsigned)f2bf(a.x) | ((unsigned)f2bf(a.y) << 16);
    o.y = (unsigned)f2bf(a.z) | ((unsigned)f2bf(a.w) << 16);
    o.z = (unsigned)f2bf(b.x) | ((unsigned)f2bf(b.y) << 16);
    o.w = (unsigned)f2bf(b.z) | ((unsigned)f2bf(b.w) << 16);
    *(uint4*)(X + m * E_ + koff) = o;
  } else if (bid < 10240){                           // hbuf = SENT (16 MB)
    int i = (bid - 6144) * 256 + tid;
    hbuf4[i] = uint4{SENT, SENT, SENT, SENT};
  } else {                                           // seq_lens: 16 blocks x 4 waves
    int w = tid >> 6, lane = tid & 63;
    int b = (bid - 10240) * 4 + w;
    int c = 0;
    for (int t = lane; t < T_; t += 64) c += (inp[b * T_ + t] != 0);
    for (int off = 32; off; off >>= 1) c += __shfl_xor(c, off);
    if (lane == 0){ lens[b] = c; out_len[b] = (float)c; }
  }
}

// ===== Z = X @ W + bias (bf16 MFMA, 128x128 tile) =====
__global__ __launch_bounds__(256) void k_gemm(const ushort* __restrict__ X,
        const ushort* __restrict__ WT, const float* __restrict__ bf_,
        const float* __restrict__ bb_, float* __restrict__ Zf, float* __restrict__ Zb){
  int zi = blockIdx.z;
  const ushort* wt = WT + zi * 262144;
  const float* bias = zi ? bb_ : bf_;
  float* Z = zi ? Zb : Zf;
  int m0 = blockIdx.x * 128, n0 = blockIdx.y * 128;
  __shared__ ushort As[128][40];
  __shared__ ushort Bs[128][40];
  int tid = threadIdx.x;
  int sr = tid >> 1, sk = (tid & 1) * 16;
  const ushort* xg = X + (m0 + sr) * E_ + sk;
  const ushort* wg = wt + (n0 + sr) * E_ + sk;
  f32x4 acc[4][4] = {};
  int lane = tid & 63, wv = tid >> 6;
  int wr = wv >> 1, wc = wv & 1;
  int lrow = lane & 15, kf = (lane >> 4) * 8;
  for (int k0 = 0; k0 < E_; k0 += 32){
    uint4 a0 = *(const uint4*)(xg + k0);
    uint4 a1 = *(const uint4*)(xg + k0 + 8);
    uint4 b0 = *(const uint4*)(wg + k0);
    uint4 b1 = *(const uint4*)(wg + k0 + 8);
    *(uint4*)&As[sr][sk]     = a0;  *(uint4*)&As[sr][sk + 8] = a1;
    *(uint4*)&Bs[sr][sk]     = b0;  *(uint4*)&Bs[sr][sk + 8] = b1;
    __syncthreads();
    bf16x8 af[4], bfr[4];
    #pragma unroll
    for (int i = 0; i < 4; i++) af[i]  = *(const bf16x8*)&As[wr * 64 + i * 16 + lrow][kf];
    #pragma unroll
    for (int i = 0; i < 4; i++) bfr[i] = *(const bf16x8*)&Bs[wc * 64 + i * 16 + lrow][kf];
    #pragma unroll
    for (int i = 0; i < 4; i++)
      #pragma unroll
      for (int j = 0; j < 4; j++)
        acc[i][j] = __builtin_amdgcn_mfma_f32_16x16x32_bf16(af[i], bfr[j], acc[i][j], 0, 0, 0);
    __syncthreads();
  }
  int crow = (lane >> 4) * 4;
  #pragma unroll
  for (int j = 0; j < 4; j++){
    int col = n0 + wc * 64 + j * 16 + lrow;
    float bv = bias[col];
    #pragma unroll
    for (int i = 0; i < 4; i++){
      int rbase = m0 + wr * 64 + i * 16 + crow;
      #pragma unroll
      for (int r = 0; r < 4; r++)
        Z[(size_t)(rbase + r) * G4 + col] = acc[i][j][r] + bv;
    }
  }
}

// ===== LSTM recurrence v4: MFMA, U-as-B-frags in regs, poll words == A-frags =====
// 32 WGs x 512 thr. bid = s*8 + g; g = dir*4 + bs (16 batches); s = col-slice (64 units).
// hbuf per group: [t][b<16][k2<128] u32, word = bf16 h[b][2k2] | h[b][2k2+1]<<16.
__global__ __launch_bounds__(512) void k_recur4(
    const float* __restrict__ Zf, const float* __restrict__ Zb,
    const ushort* __restrict__ UT, const int* __restrict__ lens,
    ushort* __restrict__ hf16, ushort* __restrict__ hb16,
    unsigned long long* hbuf){
  int bid = blockIdx.x;
  int g = bid & 7, s = bid >> 3;
  int dir = g >> 2, bs = g & 3;
  const float* Zx = dir ? Zb : Zf;
  ushort* H = dir ? hb16 : hf16;
  unsigned long long* hg = hbuf + (size_t)g * 262144;   // 256 t * 1024 u64

  int tid = threadIdx.x;
  int lane = tid & 63, wv = tid >> 6;
  int l15 = lane & 15, lq = lane >> 4;

  // ---- B-fragments: U columns for this wave's 2 N-tiles, all 8 K-blocks ----
  bf16x8 Bf[2][8];
  #pragma unroll
  for (int it = 0; it < 2; it++){
    int n = wv * 2 + it;
    int C = (n >> 2) * 256 + s * 64 + (n & 3) * 16 + l15;
    const ushort* bp = UT + dir * 262144 + C * 256 + lq * 8;
    #pragma unroll
    for (int kb = 0; kb < 8; kb++)
      Bf[it][kb] = *(const bf16x8*)(bp + kb * 32);
  }

  __shared__ float zsh[2][16 * 256];

  int u = tid & 63, bq = (tid >> 6) & 7;               // act mapping
  int bg0 = bs * 16 + bq, bg1 = bg0 + 8;
  int alen0 = lens[bg0], alen1 = lens[bg1];
  float c0 = 0.f, h0 = 0.f, c1 = 0.f, h1 = 0.f;
  int lb = l15 * 64 + lq * 2;                          // u64 poll base (per k-block +8)
  int pt = 0;

  for (int s_ = 0; s_ < 256; ++s_){
    int t = dir ? (255 - s_) : s_;
    int buf = s_ & 1;
    // 1. poll issue (A-fragments live in these u64s)
    unsigned long long A[16];
    if (s_ > 0){
      const unsigned long long* hb_ = hg + (size_t)pt * 1024;
      #pragma unroll
      for (int kb = 0; kb < 8; kb++){
        A[2*kb]   = __hip_atomic_load(hb_ + lb + kb*8,     __ATOMIC_RELAXED, __HIP_MEMORY_SCOPE_AGENT);
        A[2*kb+1] = __hip_atomic_load(hb_ + lb + kb*8 + 1, __ATOMIC_RELAXED, __HIP_MEMORY_SCOPE_AGENT);
      }
    } else {
      #pragma unroll
      for (int q = 0; q < 16; q++) A[q] = 0ull;
    }
    // 2. Z prefetch for act phase (independent of polls)
    float zr0[4], zr1[4];
    {
      const float* zp0 = Zx + (size_t)(bg0 * 256 + t) * G4 + s * 64 + u;
      const float* zp1 = Zx + (size_t)(bg1 * 256 + t) * G4 + s * 64 + u;
      #pragma unroll
      for (int g4 = 0; g4 < 4; g4++){ zr0[g4] = zp0[g4 * 256]; zr1[g4] = zp1[g4 * 256]; }
    }
    // 3. retry any sentinel words
    if (s_ > 0){
      const unsigned long long* hb_ = hg + (size_t)pt * 1024;
      #pragma unroll
      for (int q = 0; q < 16; q++){
        int kb = q >> 1, e = q & 1;
        while (__builtin_expect((unsigned)A[q] == SENT || (unsigned)(A[q] >> 32) == SENT, 0))
          A[q] = __hip_atomic_load(hb_ + lb + kb*8 + e, __ATOMIC_RELAXED, __HIP_MEMORY_SCOPE_AGENT);
      }
    }
    // 4. MFMA: z[16 x 256-slice], A shared across the wave's 2 N-tiles
    f32x4 acc0 = {0.f, 0.f, 0.f, 0.f}, acc1 = acc0;
    #pragma unroll
    for (int kb = 0; kb < 8; kb++){
      uint4v av;
      av[0] = (unsigned)A[2*kb];     av[1] = (unsigned)(A[2*kb] >> 32);
      av[2] = (unsigned)A[2*kb+1];   av[3] = (unsigned)(A[2*kb+1] >> 32);
      bf16x8 af = __builtin_bit_cast(bf16x8, av);
      acc0 = __builtin_amdgcn_mfma_f32_16x16x32_bf16(af, Bf[0][kb], acc0, 0, 0, 0);
      acc1 = __builtin_amdgcn_mfma_f32_16x16x32_bf16(af, Bf[1][kb], acc1, 0, 0, 0);
    }
    // 5. acc -> zsh (XOR-swizzled cols: 2-way banks, free)
    {
      float* zb = zsh[buf];
      int cb0 = (wv * 2 + 0) * 16 + l15;
      int cb1 = (wv * 2 + 1) * 16 + l15;
      #pragma unroll
      for (int r = 0; r < 4; r++){
        int m = lq * 4 + r;
        int sw = (m & 12) << 2;
        zb[m * 256 + (cb0 ^ sw)] = acc0[r];
        zb[m * 256 + (cb1 ^ sw)] = acc1[r];
      }
    }
    __syncthreads();
    // 6. activations: 2 batch-rows per thread
    {
      const float* zb = zsh[buf];
      int sw0 = (bq & 12) << 2;             // bq<8 -> m=bq swizzle
      int sw1 = ((bq + 8) & 12) << 2;
      float zi0 = zr0[0] + zb[bq * 256 + ((      u) ^ sw0)];
      float zf0 = zr0[1] + zb[bq * 256 + (( 64 + u) ^ sw0)];
      float zg0 = zr0[2] + zb[bq * 256 + ((128 + u) ^ sw0)];
      float zo0 = zr0[3] + zb[bq * 256 + ((192 + u) ^ sw0)];
      int m1 = bq + 8;
      float zi1 = zr1[0] + zb[m1 * 256 + ((      u) ^ sw1)];
      float zf1 = zr1[1] + zb[m1 * 256 + (( 64 + u) ^ sw1)];
      float zg1 = zr1[2] + zb[m1 * 256 + ((128 + u) ^ sw1)];
      float zo1 = zr1[3] + zb[m1 * 256 + ((192 + u) ^ sw1)];
      if (t < alen0){
        c0 = fsig(zf0) * c0 + fsig(zi0) * ftanh(zg0);
        h0 = fsig(zo0) * ftanh(c0);
      }
      if (t < alen1){
        c1 = fsig(zf1) * c1 + fsig(zi1) * ftanh(zg1);
        h1 = fsig(zo1) * ftanh(c1);
      }
      unsigned w0 = f2bf(h0), w1 = f2bf(h1);
      unsigned o0 = (unsigned)__shfl_xor((int)w0, 1);
      unsigned o1 = (unsigned)__shfl_xor((int)w1, 1);
      if (!(u & 1)){
        unsigned* hw_ = (unsigned*)(hg + (size_t)t * 1024);
        unsigned word0 = w0 | (o0 << 16);
        unsigned word1 = w1 | (o1 << 16);
        __hip_atomic_store(hw_ + bq * 128 + s * 32 + (u >> 1), word0,
                           __ATOMIC_RELAXED, __HIP_MEMORY_SCOPE_AGENT);
        __hip_atomic_store(hw_ + (bq + 8) * 128 + s * 32 + (u >> 1), word1,
                           __ATOMIC_RELAXED, __HIP_MEMORY_SCOPE_AGENT);
      }
      H[((size_t)bg0 * 256 + t) * H_ + s * 64 + u] = (ushort)w0;
      H[((size_t)bg1 * 256 + t) * H_ + s * 64 + u] = (ushort)w1;
    }
    pt = t;
  }
}

// ===== pot = [hf|hb] @ Wd + bd (one wave per row, bf16 h) =====
__global__ __launch_bounds__(256) void k_pot(const ushort* __restrict__ hf16,
        const ushort* __restrict__ hb16, const float* __restrict__ Wd,
        const float* __restrict__ bd, float* __restrict__ out, int* __restrict__ cnt){
  if (blockIdx.x == 0 && threadIdx.x == 0) *cnt = 0;
  int lane = threadIdx.x & 63, wid = threadIdx.x >> 6;
  int m = blockIdx.x * 4 + wid;
  uint2 ua = *(const uint2*)&hf16[(size_t)m * H_ + lane * 4];
  uint2 ub = *(const uint2*)&hb16[(size_t)m * H_ + lane * 4];
  float av[4] = {bf2f(ua.x & 0xFFFFu), bf2f(ua.x >> 16), bf2f(ua.y & 0xFFFFu), bf2f(ua.y >> 16)};
  float bv[4] = {bf2f(ub.x & 0xFFFFu), bf2f(ub.x >> 16), bf2f(ub.y & 0xFFFFu), bf2f(ub.y >> 16)};
  float acc[9];
  #pragma unroll
  for (int l = 0; l < 9; l++) acc[l] = 0.f;
  #pragma unroll
  for (int i = 0; i < 4; i++){
    int r = lane * 4 + i;
    #pragma unroll
    for (int l = 0; l < 9; l++)
      acc[l] += av[i] * Wd[r * 9 + l] + bv[i] * Wd[(H_ + r) * 9 + l];
  }
  #pragma unroll
  for (int off = 32; off; off >>= 1)
    #pragma unroll
    for (int l = 0; l < 9; l++) acc[l] += __shfl_xor(acc[l], off);
  if (lane == 0){
    #pragma unroll
    for (int l = 0; l < 9; l++) out[(size_t)m * 9 + l] = acc[l] + bd[l];
  }
}

// ===== CRF log-likelihood + loss (fused, last-block reduce) =====
__global__ void k_post(const float* __restrict__ out, const int* __restrict__ tags,
                       const float* __restrict__ trans, const int* __restrict__ lens,
                       float* __restrict__ lln, int* cnt, float* __restrict__ loss_out){
  int b = blockIdx.x, lane = threadIdx.x;
  int len = lens[b];
  const float* pot = out + (size_t)b * T_ * 9;
  float up = 0.f, bp = 0.f;
  for (int t = lane; t < T_; t += 64){
    int tg = tags[b * T_ + t];
    if (t < len) up += pot[t * 9 + tg];
    if (t + 1 < len){
      int tg2 = tags[b * T_ + t + 1];
      bp += trans[tg * 9 + tg2];
    }
  }
  for (int off = 32; off; off >>= 1){ up += __shfl_xor(up, off); bp += __shfl_xor(bp, off); }
  float alpha = 0.f;
  if (lane < 9){
    float tr[9];
    #pragma unroll
    for (int i = 0; i < 9; i++) tr[i] = trans[i * 9 + lane];
    alpha = pot[lane];
    for (int t = 1; t < T_; ++t){
      float v[9];
      #pragma unroll
      for (int i = 0; i < 9; i++) v[i] = __shfl(alpha, i) + tr[i];
      float mx = v[0];
      #pragma unroll
      for (int i = 1; i < 9; i++) mx = fmaxf(mx, v[i]);
      float sum = 0.f;
      #pragma unroll
      for (int i = 0; i < 9; i++) sum += __expf(v[i] - mx);
      float an = pot[t * 9 + lane] + mx + __logf(sum);
      if (t < len) alpha = an;
    }
  }
  float mx2 = -3.4e38f;
  for (int i = 0; i < 9; i++){ float a = __shfl(alpha, i); mx2 = fmaxf(mx2, a); }
  float s2 = 0.f;
  for (int i = 0; i < 9; i++){ float a = __shfl(alpha, i); s2 += __expf(a - mx2); }
  float lse = mx2 + __logf(s2);
  __shared__ int lastf;
  if (lane == 0){
    __hip_atomic_store(&lln[b], (up + bp - lse) / (float)len,
                       __ATOMIC_RELAXED, __HIP_MEMORY_SCOPE_AGENT);
    int old = __hip_atomic_fetch_add(cnt, 1, __ATOMIC_ACQ_REL, __HIP_MEMORY_SCOPE_AGENT);
    lastf = (old == 63);
  }
  __syncthreads();
  if (lastf){
    float v = __hip_atomic_load(&lln[lane], __ATOMIC_RELAXED, __HIP_MEMORY_SCOPE_AGENT);
    for (int off = 32; off; off >>= 1) v += __shfl_xor(v, off);
    if (lane == 0) loss_out[0] = -v * (1.f / 64.f);
  }
}

extern "C" void kernel_launch(void* const* d_in, const int* in_sizes, int n_in,
                              void* d_out, int out_size, void* d_ws, size_t ws_size,
                              hipStream_t stream) {
  (void)in_sizes; (void)n_in; (void)out_size; (void)ws_size;
  const int*   inp   = (const int*)  d_in[0];
  const int*   tags  = (const int*)  d_in[1];
  const float* emb   = (const float*)d_in[2];
  const float* Wf    = (const float*)d_in[3];
  const float* Uf    = (const float*)d_in[4];
  const float* bfv   = (const float*)d_in[5];
  const float* Wb    = (const float*)d_in[6];
  const float* Ub    = (const float*)d_in[7];
  const float* bbv   = (const float*)d_in[8];
  const float* Wd    = (const float*)d_in[9];
  const float* bd    = (const float*)d_in[10];
  const float* trans = (const float*)d_in[11];
  float* out = (float*)d_out;

  char* ws = (char*)d_ws;
  ushort*   UT16 = (ushort*)  (ws);                         // 1 MB
  ushort*   WT16 = (ushort*)  (ws + 1048576);               // 1 MB
  ushort*   Xbf  = (ushort*)  (ws + 2097152);               // 8 MB
  unsigned long long* hbuf = (unsigned long long*)(ws + 10485760); // 16 MB
  int*      cnt  = (int*)     (ws + 10485760);              // aliases hbuf (dead by k_pot)
  float*    Zf   = (float*)   (ws + 27262976);              // 64 MB
  float*    Zb   = (float*)   (ws + 94371840);              // 64 MB
  ushort*   hf16 = (ushort*)  (ws + 161480704);             // 8 MB
  ushort*   hb16 = (ushort*)  (ws + 169869312);             // 8 MB
  int*      lens = (int*)     (ws + 178257920);             // 256 B
  float*    lln  = (float*)   (ws + 178258176);             // 256 B

  k_prep<<<10256, 256, 0, stream>>>(inp, emb, Wf, Wb, Uf, Ub, WT16, UT16, Xbf,
                                    lens, out + 147456, (uint4*)hbuf);
  k_gemm<<<dim3(128, 8, 2), 256, 0, stream>>>(Xbf, WT16, bfv, bbv, Zf, Zb);
  k_recur4<<<32, 512, 0, stream>>>(Zf, Zb, UT16, lens, hf16, hb16, hbuf);
  k_pot<<<4096, 256, 0, stream>>>(hf16, hb16, Wd, bd, out, cnt);
  k_post<<<64, 64, 0, stream>>>(out, tags, trans, lens, lln, cnt, out + 147520);
}